// Round 2
// baseline (2460.023 us; speedup 1.0000x reference)
//
#include <hip/hip_runtime.h>
#include <cstdint>

// ElmanRNN: B=64, T=1024, I=H=256, fp32.
//   layer: xp = X @ W_ih^T + b ; h_t = tanh(xp_t + h_{t-1} @ W_hh^T)
// Plan: GEMM0 (xp0 -> ws) ; scan0 (y0 -> d_out) ; GEMM1 (xp1 -> ws) ; scan1 (-> d_out)
// Requires ws_size >= 64 MB (M*H*4 bytes).
//
// R2: scan restructured — 512 thr/block, K-half split per output row,
// shfl_xor(1) reduction (no barrier), double-buffered h (ONE barrier/step),
// distributed tanh/stores, 2-step-deep xp register prefetch.

#define HDIM 256
#define TLEN 1024
#define BATCH 64

// ---------------------------------------------------------------------------
// Input-projection GEMM: C[m][n] = bias[n] + sum_k X[m][k] * W[n][k]
// M = 65536, N = K = 256.  BLK_M=128, BLK_N=64, BLK_K=16, 256 threads, 8x4 microtile.
// ---------------------------------------------------------------------------
__global__ __launch_bounds__(256) void proj_gemm(
    const float* __restrict__ X,
    const float* __restrict__ W,
    const float* __restrict__ bias,
    float* __restrict__ C, int M)
{
    __shared__ __align__(16) float Ast[16][136];
    __shared__ __align__(16) float Bst[16][68];

    const int tid = threadIdx.x;
    const int tx  = tid & 15;
    const int ty  = tid >> 4;
    const int m0  = blockIdx.x * 128;
    const int n0  = blockIdx.y * 64;

    float acc[8][4];
#pragma unroll
    for (int i = 0; i < 8; ++i)
#pragma unroll
        for (int j = 0; j < 4; ++j) acc[i][j] = 0.f;

    const int ar = tid >> 1;
    const int ah = (tid & 1) * 8;
    const int bn = tid >> 2;
    const int bg = (tid & 3) * 4;

    for (int kc = 0; kc < 16; ++kc) {
        const int k0 = kc * 16;
        const float4 av0 = *reinterpret_cast<const float4*>(&X[(size_t)(m0 + ar) * HDIM + k0 + ah]);
        const float4 av1 = *reinterpret_cast<const float4*>(&X[(size_t)(m0 + ar) * HDIM + k0 + ah + 4]);
        const float4 bv  = *reinterpret_cast<const float4*>(&W[(size_t)(n0 + bn) * HDIM + k0 + bg]);
        __syncthreads();
        Ast[ah + 0][ar] = av0.x; Ast[ah + 1][ar] = av0.y;
        Ast[ah + 2][ar] = av0.z; Ast[ah + 3][ar] = av0.w;
        Ast[ah + 4][ar] = av1.x; Ast[ah + 5][ar] = av1.y;
        Ast[ah + 6][ar] = av1.z; Ast[ah + 7][ar] = av1.w;
        Bst[bg + 0][bn] = bv.x;  Bst[bg + 1][bn] = bv.y;
        Bst[bg + 2][bn] = bv.z;  Bst[bg + 3][bn] = bv.w;
        __syncthreads();
#pragma unroll
        for (int kk = 0; kk < 16; ++kk) {
            const float4 a0 = *reinterpret_cast<const float4*>(&Ast[kk][ty * 8]);
            const float4 a1 = *reinterpret_cast<const float4*>(&Ast[kk][ty * 8 + 4]);
            const float4 b4 = *reinterpret_cast<const float4*>(&Bst[kk][tx * 4]);
            const float av[8] = {a0.x, a0.y, a0.z, a0.w, a1.x, a1.y, a1.z, a1.w};
            const float bb[4] = {b4.x, b4.y, b4.z, b4.w};
#pragma unroll
            for (int i = 0; i < 8; ++i)
#pragma unroll
                for (int j = 0; j < 4; ++j)
                    acc[i][j] = fmaf(av[i], bb[j], acc[i][j]);
        }
    }

    const float4 bias4 = *reinterpret_cast<const float4*>(&bias[n0 + tx * 4]);
    const float bb[4] = {bias4.x, bias4.y, bias4.z, bias4.w};
#pragma unroll
    for (int i = 0; i < 8; ++i) {
        float4 o;
        o.x = acc[i][0] + bb[0];
        o.y = acc[i][1] + bb[1];
        o.z = acc[i][2] + bb[2];
        o.w = acc[i][3] + bb[3];
        *reinterpret_cast<float4*>(&C[(size_t)(m0 + ty * 8 + i) * HDIM + n0 + tx * 4]) = o;
    }
}

// ---------------------------------------------------------------------------
// Recurrent scan, R2 structure.
//   512 threads: thread (j = tid>>1, half = tid&1) owns W_hh[j][half*128..+127]
//   in 32 float4 registers. h double-buffered in LDS; one barrier per step.
//   Pair-reduce via shfl_xor(1). Even lane writes h, odd lane writes y.
// ---------------------------------------------------------------------------
__device__ __forceinline__ float fast_tanh(float x)
{
    const float xc = fminf(fmaxf(x, -15.f), 15.f);
    const float e  = __expf(2.f * xc);
    return (e - 1.f) / (e + 1.f);
}

__device__ __forceinline__ float dot128(const float4* __restrict__ w,
                                        const float*  __restrict__ hb)
{
    const float4* h4 = reinterpret_cast<const float4*>(hb);
    float s0 = 0.f, s1 = 0.f, s2 = 0.f, s3 = 0.f;
#pragma unroll
    for (int c = 0; c < 32; c += 4) {
        const float4 h0 = h4[c + 0];
        const float4 h1 = h4[c + 1];
        const float4 h2 = h4[c + 2];
        const float4 h3 = h4[c + 3];
        s0 = fmaf(w[c + 0].x, h0.x, s0); s0 = fmaf(w[c + 0].y, h0.y, s0);
        s0 = fmaf(w[c + 0].z, h0.z, s0); s0 = fmaf(w[c + 0].w, h0.w, s0);
        s1 = fmaf(w[c + 1].x, h1.x, s1); s1 = fmaf(w[c + 1].y, h1.y, s1);
        s1 = fmaf(w[c + 1].z, h1.z, s1); s1 = fmaf(w[c + 1].w, h1.w, s1);
        s2 = fmaf(w[c + 2].x, h2.x, s2); s2 = fmaf(w[c + 2].y, h2.y, s2);
        s2 = fmaf(w[c + 2].z, h2.z, s2); s2 = fmaf(w[c + 2].w, h2.w, s2);
        s3 = fmaf(w[c + 3].x, h3.x, s3); s3 = fmaf(w[c + 3].y, h3.y, s3);
        s3 = fmaf(w[c + 3].z, h3.z, s3); s3 = fmaf(w[c + 3].w, h3.w, s3);
    }
    return (s0 + s1) + (s2 + s3);
}

__global__ __launch_bounds__(512, 2) void elman_scan(
    const float* __restrict__ xp,   // [B, T, H]
    const float* __restrict__ Whh,  // [H, H]
    float* __restrict__ y,          // [B, T, H]
    int T)
{
    const int b    = blockIdx.x;
    const int tid  = threadIdx.x;
    const int j    = tid >> 1;
    const int half = tid & 1;

    float4 w[32];
    const float4* wp = reinterpret_cast<const float4*>(Whh + (size_t)j * HDIM + half * 128);
#pragma unroll
    for (int c = 0; c < 32; ++c) w[c] = wp[c];

    __shared__ __align__(16) float hbuf[2][HDIM];

    const float* xrow = xp + (size_t)b * T * HDIM;
    float*       yrow = y  + (size_t)b * T * HDIM;

    if (half == 0) hbuf[0][j] = 0.f;
    float x0 = xrow[j];                 // xp[t=0][j]
    float x1 = xrow[HDIM + j];          // xp[t=1][j]
    __syncthreads();

    for (int t = 0; t < T; t += 2) {
        // ---- sub-step t (even): read hbuf[0], write hbuf[1] ----
        {
            const float xnew = (t + 2 < T) ? xrow[(size_t)(t + 2) * HDIM + j] : 0.f;
            float s = dot128(w, &hbuf[0][half * 128]);
            s += __shfl_xor(s, 1);
            const float hn = fast_tanh(s + x0);
            if (half == 0) hbuf[1][j] = hn;
            else           yrow[(size_t)t * HDIM + j] = hn;
            x0 = xnew;
            __syncthreads();
        }
        // ---- sub-step t+1 (odd): read hbuf[1], write hbuf[0] ----
        {
            const float xnew = (t + 3 < T) ? xrow[(size_t)(t + 3) * HDIM + j] : 0.f;
            float s = dot128(w, &hbuf[1][half * 128]);
            s += __shfl_xor(s, 1);
            const float hn = fast_tanh(s + x1);
            if (half == 0) hbuf[0][j] = hn;
            else           yrow[(size_t)(t + 1) * HDIM + j] = hn;
            x1 = xnew;
            __syncthreads();
        }
    }
}

// ---------------------------------------------------------------------------
extern "C" void kernel_launch(void* const* d_in, const int* in_sizes, int n_in,
                              void* d_out, int out_size, void* d_ws, size_t ws_size,
                              hipStream_t stream)
{
    const float* x     = (const float*)d_in[0];
    const float* W_ih0 = (const float*)d_in[1];
    const float* b_ih0 = (const float*)d_in[2];
    const float* W_hh0 = (const float*)d_in[3];
    const float* W_ih1 = (const float*)d_in[4];
    const float* b_ih1 = (const float*)d_in[5];
    const float* W_hh1 = (const float*)d_in[6];

    float* out = (float*)d_out;
    float* xp  = (float*)d_ws;          // needs 64 MB

    const int M = BATCH * TLEN;
    dim3 ggrid(M / 128, HDIM / 64);

    proj_gemm<<<ggrid, 256, 0, stream>>>(x,   W_ih0, b_ih0, xp, M);
    elman_scan<<<BATCH, 512, 0, stream>>>(xp, W_hh0, out, TLEN);
    proj_gemm<<<ggrid, 256, 0, stream>>>(out, W_ih1, b_ih1, xp, M);
    elman_scan<<<BATCH, 512, 0, stream>>>(xp, W_hh1, out, TLEN);
}

// Round 3
// 1772.719 us; speedup vs baseline: 1.3877x; 1.3877x over previous
//
#include <hip/hip_runtime.h>
#include <cstdint>

// ElmanRNN: B=64, T=1024, I=H=256, fp32.
//   layer: xp = X @ W_ih^T + b ; h_t = tanh(xp_t + h_{t-1} @ W_hh^T)
// Plan: GEMM0 (xp0 -> ws) ; scan0 (y0 -> d_out) ; GEMM1 (xp1 -> ws) ; scan1 (-> d_out)
// Requires ws_size >= 64 MB.
//
// R3 scan: 1024 thr / 16 waves. Lane l of wave w: output j = w*16 + (l>>2),
// K-quarter q = l&3 (INTRA-wave reduction via 2x shfl_xor — no cross-wave LDS
// reduce, no serial tail). Weights 16xfloat4 = 64 VGPR pinned by
// __launch_bounds__(1024,4) cap=128. h double-buffered in LDS with quarter
// stride 68 (4 broadcast addrs -> disjoint bank groups, 0 conflicts).
// One barrier/step. xp register-prefetched 4 steps deep.

#define HDIM 256
#define TLEN 1024
#define BATCH 64
#define HQ 68   // padded LDS quarter stride (floats); 68*4B=272B, 16B-aligned

// ---------------------------------------------------------------------------
// Input-projection GEMM (unchanged from R1).
// ---------------------------------------------------------------------------
__global__ __launch_bounds__(256) void proj_gemm(
    const float* __restrict__ X,
    const float* __restrict__ W,
    const float* __restrict__ bias,
    float* __restrict__ C, int M)
{
    __shared__ __align__(16) float Ast[16][136];
    __shared__ __align__(16) float Bst[16][68];

    const int tid = threadIdx.x;
    const int tx  = tid & 15;
    const int ty  = tid >> 4;
    const int m0  = blockIdx.x * 128;
    const int n0  = blockIdx.y * 64;

    float acc[8][4];
#pragma unroll
    for (int i = 0; i < 8; ++i)
#pragma unroll
        for (int j = 0; j < 4; ++j) acc[i][j] = 0.f;

    const int ar = tid >> 1;
    const int ah = (tid & 1) * 8;
    const int bn = tid >> 2;
    const int bg = (tid & 3) * 4;

    for (int kc = 0; kc < 16; ++kc) {
        const int k0 = kc * 16;
        const float4 av0 = *reinterpret_cast<const float4*>(&X[(size_t)(m0 + ar) * HDIM + k0 + ah]);
        const float4 av1 = *reinterpret_cast<const float4*>(&X[(size_t)(m0 + ar) * HDIM + k0 + ah + 4]);
        const float4 bv  = *reinterpret_cast<const float4*>(&W[(size_t)(n0 + bn) * HDIM + k0 + bg]);
        __syncthreads();
        Ast[ah + 0][ar] = av0.x; Ast[ah + 1][ar] = av0.y;
        Ast[ah + 2][ar] = av0.z; Ast[ah + 3][ar] = av0.w;
        Ast[ah + 4][ar] = av1.x; Ast[ah + 5][ar] = av1.y;
        Ast[ah + 6][ar] = av1.z; Ast[ah + 7][ar] = av1.w;
        Bst[bg + 0][bn] = bv.x;  Bst[bg + 1][bn] = bv.y;
        Bst[bg + 2][bn] = bv.z;  Bst[bg + 3][bn] = bv.w;
        __syncthreads();
#pragma unroll
        for (int kk = 0; kk < 16; ++kk) {
            const float4 a0 = *reinterpret_cast<const float4*>(&Ast[kk][ty * 8]);
            const float4 a1 = *reinterpret_cast<const float4*>(&Ast[kk][ty * 8 + 4]);
            const float4 b4 = *reinterpret_cast<const float4*>(&Bst[kk][tx * 4]);
            const float av[8] = {a0.x, a0.y, a0.z, a0.w, a1.x, a1.y, a1.z, a1.w};
            const float bb[4] = {b4.x, b4.y, b4.z, b4.w};
#pragma unroll
            for (int i = 0; i < 8; ++i)
#pragma unroll
                for (int j = 0; j < 4; ++j)
                    acc[i][j] = fmaf(av[i], bb[j], acc[i][j]);
        }
    }

    const float4 bias4 = *reinterpret_cast<const float4*>(&bias[n0 + tx * 4]);
    const float bb[4] = {bias4.x, bias4.y, bias4.z, bias4.w};
#pragma unroll
    for (int i = 0; i < 8; ++i) {
        float4 o;
        o.x = acc[i][0] + bb[0];
        o.y = acc[i][1] + bb[1];
        o.z = acc[i][2] + bb[2];
        o.w = acc[i][3] + bb[3];
        *reinterpret_cast<float4*>(&C[(size_t)(m0 + ty * 8 + i) * HDIM + n0 + tx * 4]) = o;
    }
}

// ---------------------------------------------------------------------------
// R3 recurrent scan.
// ---------------------------------------------------------------------------
__device__ __forceinline__ float fast_tanh(float x)
{
    const float xc = fminf(fmaxf(x, -15.f), 15.f);
    const float e  = __expf(2.f * xc);
    return (e - 1.f) / (e + 1.f);
}

__global__ __launch_bounds__(1024, 4) void elman_scan(
    const float* __restrict__ xp,   // [B, T, H]
    const float* __restrict__ Whh,  // [H, H]
    float* __restrict__ y,          // [B, T, H]
    int T)
{
    const int b    = blockIdx.x;
    const int tid  = threadIdx.x;
    const int lane = tid & 63;
    const int wave = tid >> 6;
    const int j    = wave * 16 + (lane >> 2);   // output index 0..255
    const int q    = lane & 3;                  // K-quarter (wave-lane local)

    // W_hh[j][q*64 .. q*64+63] in registers: 16 float4 = 64 VGPR.
    float4 w[16];
    {
        const float4* wp = reinterpret_cast<const float4*>(Whh + (size_t)j * HDIM + q * 64);
#pragma unroll
        for (int c = 0; c < 16; ++c) w[c] = wp[c];
    }

    // h double buffer; quarter q lives at offset q*HQ (HQ=68 -> disjoint banks).
    __shared__ __align__(16) float hbuf[2][4 * HQ];

    const float* xrow = xp + (size_t)b * T * HDIM;
    float*       yrow = y  + (size_t)b * T * HDIM;

    const int hpos = (j >> 6) * HQ + (j & 63);  // where h_j lives
    if (q == 0) hbuf[0][hpos] = 0.f;

    // xp prefetch, 4 steps deep (each 4-lane group loads the same 4B -> one
    // 64B segment per wave per step).
    float xv[4];
#pragma unroll
    for (int p = 0; p < 4; ++p) xv[p] = xrow[(size_t)p * HDIM + j];

    __syncthreads();

    int cur = 0;
    for (int t = 0; t < T; t += 4) {
#pragma unroll
        for (int p = 0; p < 4; ++p) {
            // issue prefetch for t+p+4 immediately (consumed 4 barriers later)
            int tf = t + p + 4; tf = (tf < T) ? tf : (T - 1);
            const float xnew = xrow[(size_t)tf * HDIM + j];

            // 64-wide partial dot from LDS broadcast reads
            const float* hb = &hbuf[cur][q * HQ];
            float s0 = 0.f, s1 = 0.f, s2 = 0.f, s3 = 0.f;
#pragma unroll
            for (int c = 0; c < 16; c += 4) {
                const float4 h0 = *reinterpret_cast<const float4*>(hb + (c + 0) * 4);
                const float4 h1 = *reinterpret_cast<const float4*>(hb + (c + 1) * 4);
                const float4 h2 = *reinterpret_cast<const float4*>(hb + (c + 2) * 4);
                const float4 h3 = *reinterpret_cast<const float4*>(hb + (c + 3) * 4);
                s0 = fmaf(w[c + 0].x, h0.x, s0); s0 = fmaf(w[c + 0].y, h0.y, s0);
                s0 = fmaf(w[c + 0].z, h0.z, s0); s0 = fmaf(w[c + 0].w, h0.w, s0);
                s1 = fmaf(w[c + 1].x, h1.x, s1); s1 = fmaf(w[c + 1].y, h1.y, s1);
                s1 = fmaf(w[c + 1].z, h1.z, s1); s1 = fmaf(w[c + 1].w, h1.w, s1);
                s2 = fmaf(w[c + 2].x, h2.x, s2); s2 = fmaf(w[c + 2].y, h2.y, s2);
                s2 = fmaf(w[c + 2].z, h2.z, s2); s2 = fmaf(w[c + 2].w, h2.w, s2);
                s3 = fmaf(w[c + 3].x, h3.x, s3); s3 = fmaf(w[c + 3].y, h3.y, s3);
                s3 = fmaf(w[c + 3].z, h3.z, s3); s3 = fmaf(w[c + 3].w, h3.w, s3);
            }
            float s = (s0 + s1) + (s2 + s3);

            // intra-wave 4-lane reduction (DPP shuffles, no barrier)
            s += __shfl_xor(s, 1);
            s += __shfl_xor(s, 2);

            const float hn = fast_tanh(s + xv[p]);

            if (q == 0)      hbuf[cur ^ 1][hpos] = hn;
            else if (q == 1) yrow[(size_t)(t + p) * HDIM + j] = hn;

            xv[p] = xnew;
            cur ^= 1;
            __syncthreads();
        }
    }
}

// ---------------------------------------------------------------------------
extern "C" void kernel_launch(void* const* d_in, const int* in_sizes, int n_in,
                              void* d_out, int out_size, void* d_ws, size_t ws_size,
                              hipStream_t stream)
{
    const float* x     = (const float*)d_in[0];
    const float* W_ih0 = (const float*)d_in[1];
    const float* b_ih0 = (const float*)d_in[2];
    const float* W_hh0 = (const float*)d_in[3];
    const float* W_ih1 = (const float*)d_in[4];
    const float* b_ih1 = (const float*)d_in[5];
    const float* W_hh1 = (const float*)d_in[6];

    float* out = (float*)d_out;
    float* xp  = (float*)d_ws;          // needs 64 MB

    const int M = BATCH * TLEN;
    dim3 ggrid(M / 128, HDIM / 64);

    proj_gemm<<<ggrid, 256, 0, stream>>>(x,   W_ih0, b_ih0, xp, M);
    elman_scan<<<BATCH, 1024, 0, stream>>>(xp, W_hh0, out, TLEN);
    proj_gemm<<<ggrid, 256, 0, stream>>>(out, W_ih1, b_ih1, xp, M);
    elman_scan<<<BATCH, 1024, 0, stream>>>(xp, W_hh1, out, TLEN);
}